// Round 1
// baseline (406.287 us; speedup 1.0000x reference)
//
#include <hip/hip_runtime.h>

typedef unsigned short ushort_t;
typedef __attribute__((ext_vector_type(8))) short short8;
typedef __attribute__((ext_vector_type(4))) float f32x4;

__device__ __forceinline__ ushort_t f2bf(float f) {
  union { float f; unsigned int u; } v; v.f = f;
  unsigned int u = v.u;
  unsigned int r = (u + 0x7fffu + ((u >> 16) & 1u)) >> 16;
  return (ushort_t)r;
}

__device__ __forceinline__ void load_lds16(const void* g, void* l) {
  __builtin_amdgcn_global_load_lds(
      (const __attribute__((address_space(1))) unsigned int*)g,
      (__attribute__((address_space(3))) unsigned int*)l, 16, 0, 0);
}

// ---------------- elementwise f32 -> bf16 ----------------
__global__ __launch_bounds__(256) void cvt_f32_to_bf16_vec(
    const float* __restrict__ in, ushort_t* __restrict__ out, int n8) {
  int i = blockIdx.x * 256 + threadIdx.x;
  if (i >= n8) return;
  const float4* p = (const float4*)in;
  float4 a = p[2 * i];
  float4 b = p[2 * i + 1];
  short8 v;
  v[0] = (short)f2bf(a.x); v[1] = (short)f2bf(a.y);
  v[2] = (short)f2bf(a.z); v[3] = (short)f2bf(a.w);
  v[4] = (short)f2bf(b.x); v[5] = (short)f2bf(b.y);
  v[6] = (short)f2bf(b.z); v[7] = (short)f2bf(b.w);
  *(short8*)(out + (size_t)i * 8) = v;
}

// ---------------- transpose f32 [R][C] -> bf16 [C][R] ----------------
__global__ __launch_bounds__(256) void transpose_to_bf16(
    const float* __restrict__ in, ushort_t* __restrict__ out, int R, int C) {
  __shared__ float tile[64][65];
  int c0 = blockIdx.x * 64, r0 = blockIdx.y * 64;
  int tid = threadIdx.x;
  for (int it = 0; it < 16; ++it) {
    int l = it * 256 + tid;
    int r = l >> 6, c = l & 63;
    tile[r][c] = in[(size_t)(r0 + r) * C + c0 + c];
  }
  __syncthreads();
  for (int it = 0; it < 16; ++it) {
    int l = it * 256 + tid;
    int ro = l >> 6, co = l & 63;
    out[(size_t)(c0 + ro) * R + r0 + co] = f2bf(tile[co][ro]);
  }
}

// ---------------- m97-style gemm_bt core: C[128x128] = A[M][K] * Bt[N][K]^T ----
// LDS layout: A planes [2][128][32] (ks-halves), B same at +8192 elems.
__device__ __forceinline__ void gemm_bt_main(
    const ushort_t* __restrict__ A, const ushort_t* __restrict__ Bt,
    int K, int bm, int bn, ushort_t* lds, f32x4 acc[4][4]) {
  const int tid = threadIdx.x;
  const int wave = tid >> 6, lane = tid & 63;
  const int quad = lane >> 4, col = lane & 15;
  const int wm = (wave & 1) * 64, wn = (wave >> 1) * 64;
  ushort_t* ldsA = lds;
  ushort_t* ldsB = lds + 8192;
  f32x4 z = {0.f, 0.f, 0.f, 0.f};
  for (int i = 0; i < 4; ++i)
    for (int j = 0; j < 4; ++j) acc[i][j] = z;
  for (int bk = 0; bk < K; bk += 64) {
    for (int is = 0; is < 4; ++is) {
      int o = is * 4096 + wave * 1024 + lane * 16;  // byte offset in 16KB tile
      int p = o >> 13;
      int w = o & 8191;
      int r = w >> 6, kk = (w & 63) >> 1;
      int ldso = (is * 4096 + wave * 1024) >> 1;  // uniform elem offset
      const ushort_t* ga = A + (size_t)(bm + r) * K + bk + p * 32 + kk;
      load_lds16(ga, ldsA + ldso);
      const ushort_t* gb = Bt + (size_t)(bn + r) * K + bk + p * 32 + kk;
      load_lds16(gb, ldsB + ldso);
    }
    __syncthreads();
    for (int ks = 0; ks < 2; ++ks) {
      short8 af[4], bfr[4];
      for (int i = 0; i < 4; ++i)
        af[i] = *(const short8*)(ldsA + ks * 4096 + (wm + i * 16 + col) * 32 + quad * 8);
      for (int j = 0; j < 4; ++j)
        bfr[j] = *(const short8*)(ldsB + ks * 4096 + (wn + j * 16 + col) * 32 + quad * 8);
      for (int i = 0; i < 4; ++i)
        for (int j = 0; j < 4; ++j)
          acc[i][j] = __builtin_amdgcn_mfma_f32_16x16x32_bf16(af[i], bfr[j], acc[i][j], 0, 0, 0);
    }
    __syncthreads();
  }
}

// ---------------- GEMM1: X*W1t^T + b -> Q [bh][t][64], K [bh][t][64], Vt [bh][64][t]
__global__ __launch_bounds__(256) void gemm_qkv(
    const ushort_t* __restrict__ Xb, const ushort_t* __restrict__ W1t,
    const float* __restrict__ bias, ushort_t* __restrict__ Qb,
    ushort_t* __restrict__ Kb, ushort_t* __restrict__ Vtb) {
  __shared__ ushort_t lds[16384];
  const int ntile = 3072 / 128;
  int bn = (blockIdx.x % ntile) * 128;
  int bm = (blockIdx.x / ntile) * 128;
  f32x4 acc[4][4];
  gemm_bt_main(Xb, W1t, 1024, bm, bn, lds, acc);
  const int tid = threadIdx.x, wave = tid >> 6, lane = tid & 63;
  const int quad = lane >> 4, col = lane & 15;
  const int wm = (wave & 1) * 64, wn = (wave >> 1) * 64;
  int which = bn >> 10;  // 0=q, 1=k, 2=v (uniform per block)
  for (int i = 0; i < 4; ++i) {
    int row0 = bm + wm + i * 16 + quad * 4;
    int b = row0 >> 11, t0 = row0 & 2047;
    for (int j = 0; j < 4; ++j) {
      int cg = bn + wn + j * 16 + col;
      float bv = bias[cg];
      int rem = cg & 1023;
      int h = rem >> 6, hd = rem & 63;
      size_t bh = (size_t)(b * 16 + h);
      if (which == 0) {
        for (int r = 0; r < 4; ++r)
          Qb[(bh * 2048 + t0 + r) * 64 + hd] = f2bf(acc[i][j][r] + bv);
      } else if (which == 1) {
        for (int r = 0; r < 4; ++r)
          Kb[(bh * 2048 + t0 + r) * 64 + hd] = f2bf(acc[i][j][r] + bv);
      } else {
        ushort4 pk;
        pk.x = f2bf(acc[i][j][0] + bv);
        pk.y = f2bf(acc[i][j][1] + bv);
        pk.z = f2bf(acc[i][j][2] + bv);
        pk.w = f2bf(acc[i][j][3] + bv);
        *(ushort4*)(Vtb + (bh * 64 + hd) * 2048 + t0) = pk;
      }
    }
  }
}

// ---------------- GEMM2: Y*W2t^T + b -> out (fp32) ----------------
__global__ __launch_bounds__(256) void gemm_out_k(
    const ushort_t* __restrict__ Yb, const ushort_t* __restrict__ W2t,
    const float* __restrict__ bias, float* __restrict__ out) {
  __shared__ ushort_t lds[16384];
  const int ntile = 1024 / 128;
  int bn = (blockIdx.x % ntile) * 128;
  int bm = (blockIdx.x / ntile) * 128;
  f32x4 acc[4][4];
  gemm_bt_main(Yb, W2t, 1024, bm, bn, lds, acc);
  const int tid = threadIdx.x, wave = tid >> 6, lane = tid & 63;
  const int quad = lane >> 4, col = lane & 15;
  const int wm = (wave & 1) * 64, wn = (wave >> 1) * 64;
  for (int i = 0; i < 4; ++i) {
    int row0 = bm + wm + i * 16 + quad * 4;
    for (int j = 0; j < 4; ++j) {
      int cg = bn + wn + j * 16 + col;
      float bv = bias[cg];
      for (int r = 0; r < 4; ++r)
        out[(size_t)(row0 + r) * 1024 + cg] = acc[i][j][r] + bv;
    }
  }
}

// ---------------- flash attention ----------------
// Q,K: [bh][2048][64] bf16; Vt: [bh][64][2048] bf16; Y: [b][t][1024] bf16.
// Block: 128 queries of one (b,h); 4 waves x 32q. k-tiles of 128, causal.
#define KS_OFF 0       // K tile [128][72]
#define VS_OFF 9216    // Vt tile [64][136]
#define PS_OFF 17920   // P tile [128][152] (aliased with Q staging [128][72])
__global__ __launch_bounds__(256) void attn(
    const ushort_t* __restrict__ Qb, const ushort_t* __restrict__ Kb,
    const ushort_t* __restrict__ Vtb, ushort_t* __restrict__ Yb) {
  __shared__ ushort_t lds[37376];
  const int tid = threadIdx.x, wave = tid >> 6, lane = tid & 63;
  const int quad = lane >> 4, col = lane & 15;
  int bh = blockIdx.x & 63;
  int qt = 15 - (blockIdx.x >> 6);  // long blocks dispatch first
  int q0 = qt * 128;
  int b = bh >> 4, h = bh & 15;
  const ushort_t* Qg = Qb + (size_t)bh * 2048 * 64;
  const ushort_t* Kg = Kb + (size_t)bh * 2048 * 64;
  const ushort_t* Vg = Vtb + (size_t)bh * 64 * 2048;

  // stage Q tile (stride 72) into P region, then cache frags in regs
  for (int it = 0; it < 4; ++it) {
    int v = it * 256 + tid;
    int r = v >> 3, co = (v & 7) * 8;
    short8 val = *(const short8*)(Qg + (size_t)(q0 + r) * 64 + co);
    *(short8*)(lds + PS_OFF + r * 72 + co) = val;
  }
  __syncthreads();
  short8 qf[2][2];
  for (int i = 0; i < 2; ++i)
    for (int ks = 0; ks < 2; ++ks)
      qf[i][ks] = *(const short8*)(lds + PS_OFF + (wave * 32 + i * 16 + col) * 72 + ks * 32 + quad * 8);

  f32x4 z = {0.f, 0.f, 0.f, 0.f};
  f32x4 oacc[2][4];
  float mst[2][4], lst[2][4];
  for (int i = 0; i < 2; ++i) {
    for (int jo = 0; jo < 4; ++jo) oacc[i][jo] = z;
    for (int r = 0; r < 4; ++r) { mst[i][r] = -3.0e38f; lst[i][r] = 0.f; }
  }
  const float CL = 0.18033688011112042f;  // 0.125 * log2(e)

  for (int kt = 0; kt <= qt; ++kt) {
    int k0 = kt * 128;
    __syncthreads();  // prev iter's LDS reads done (also covers qf loads at kt=0)
    for (int it = 0; it < 4; ++it) {  // K tile
      int v = it * 256 + tid;
      int r = v >> 3, co = (v & 7) * 8;
      short8 val = *(const short8*)(Kg + (size_t)(k0 + r) * 64 + co);
      *(short8*)(lds + KS_OFF + r * 72 + co) = val;
    }
    for (int it = 0; it < 4; ++it) {  // Vt tile
      int v = it * 256 + tid;
      int r = v >> 4, co = (v & 15) * 8;
      short8 val = *(const short8*)(Vg + (size_t)r * 2048 + k0 + co);
      *(short8*)(lds + VS_OFF + r * 136 + co) = val;
    }
    __syncthreads();
    // S = Q K^T  (per wave: 32q x 128k)
    f32x4 s[2][8];
    for (int i = 0; i < 2; ++i)
      for (int j = 0; j < 8; ++j) s[i][j] = z;
    for (int ks = 0; ks < 2; ++ks)
      for (int j = 0; j < 8; ++j) {
        short8 kf = *(const short8*)(lds + KS_OFF + (j * 16 + col) * 72 + ks * 32 + quad * 8);
        for (int i = 0; i < 2; ++i)
          s[i][j] = __builtin_amdgcn_mfma_f32_16x16x32_bf16(qf[i][ks], kf, s[i][j], 0, 0, 0);
      }
    if (kt == qt) {  // diagonal causal mask
      for (int i = 0; i < 2; ++i) {
        int qrow0 = q0 + wave * 32 + i * 16 + quad * 4;
        for (int j = 0; j < 8; ++j) {
          int key = k0 + j * 16 + col;
          for (int r = 0; r < 4; ++r)
            if (key > qrow0 + r) s[i][j][r] = -3.0e38f;
        }
      }
    }
    // online softmax (rows live in 16-lane quad groups)
    for (int i = 0; i < 2; ++i) {
      for (int r = 0; r < 4; ++r) {
        float rm = s[i][0][r];
        for (int j = 1; j < 8; ++j) rm = fmaxf(rm, s[i][j][r]);
        rm = fmaxf(rm, __shfl_xor(rm, 1));
        rm = fmaxf(rm, __shfl_xor(rm, 2));
        rm = fmaxf(rm, __shfl_xor(rm, 4));
        rm = fmaxf(rm, __shfl_xor(rm, 8));
        float mnew = fmaxf(mst[i][r], rm);
        float alpha = __builtin_amdgcn_exp2f((mst[i][r] - mnew) * CL);
        mst[i][r] = mnew;
        float rs = 0.f;
        for (int j = 0; j < 8; ++j) {
          float p = __builtin_amdgcn_exp2f((s[i][j][r] - mnew) * CL);
          s[i][j][r] = p;
          rs += p;
        }
        rs += __shfl_xor(rs, 1);
        rs += __shfl_xor(rs, 2);
        rs += __shfl_xor(rs, 4);
        rs += __shfl_xor(rs, 8);
        lst[i][r] = lst[i][r] * alpha + rs;
        for (int jo = 0; jo < 4; ++jo) oacc[i][jo][r] *= alpha;
      }
    }
    // write P (bf16) to wave-private LDS rows, stride 152
    for (int i = 0; i < 2; ++i)
      for (int j = 0; j < 8; ++j)
        for (int r = 0; r < 4; ++r)
          lds[PS_OFF + (wave * 32 + i * 16 + quad * 4 + r) * 152 + j * 16 + col] =
              f2bf(s[i][j][r]);
    // O += P V
    for (int ks = 0; ks < 4; ++ks) {
      short8 pf[2];
      for (int i = 0; i < 2; ++i)
        pf[i] = *(const short8*)(lds + PS_OFF + (wave * 32 + i * 16 + col) * 152 + ks * 32 + quad * 8);
      for (int jo = 0; jo < 4; ++jo) {
        short8 vf = *(const short8*)(lds + VS_OFF + (jo * 16 + col) * 136 + ks * 32 + quad * 8);
        for (int i = 0; i < 2; ++i)
          oacc[i][jo] = __builtin_amdgcn_mfma_f32_16x16x32_bf16(pf[i], vf, oacc[i][jo], 0, 0, 0);
      }
    }
  }
  // normalize + store Y [b][t][1024]
  for (int i = 0; i < 2; ++i) {
    for (int r = 0; r < 4; ++r) {
      float rinv = 1.0f / lst[i][r];
      int t = q0 + wave * 32 + i * 16 + quad * 4 + r;
      size_t rowbase = ((size_t)(b * 2048 + t)) * 1024 + h * 64;
      for (int jo = 0; jo < 4; ++jo)
        Yb[rowbase + jo * 16 + col] = f2bf(oacc[i][jo][r] * rinv);
    }
  }
}

extern "C" void kernel_launch(void* const* d_in, const int* in_sizes, int n_in,
                              void* d_out, int out_size, void* d_ws, size_t ws_size,
                              hipStream_t stream) {
  const float* x     = (const float*)d_in[0];
  const float* qkv_w = (const float*)d_in[1];
  const float* qkv_b = (const float*)d_in[2];
  const float* o_w   = (const float*)d_in[3];
  const float* o_b   = (const float*)d_in[4];
  float* out = (float*)d_out;
  char* ws = (char*)d_ws;
  // workspace layout (bytes)
  ushort_t* Xb  = (ushort_t*)(ws);              // 16 MB (aliased as Yb later)
  ushort_t* W1t = (ushort_t*)(ws + 16777216);   // 6 MB  [3072][1024]
  ushort_t* W2t = (ushort_t*)(ws + 23068672);   // 2 MB  [1024][1024]
  ushort_t* Qb  = (ushort_t*)(ws + 25165824);   // 16 MB [64][2048][64]
  ushort_t* Kb  = (ushort_t*)(ws + 41943040);   // 16 MB
  ushort_t* Vtb = (ushort_t*)(ws + 58720256);   // 16 MB [64][64][2048]
  ushort_t* Yb  = Xb;                           // alias: X dead after gemm_qkv

  cvt_f32_to_bf16_vec<<<4096, 256, 0, stream>>>(x, Xb, 1048576);
  transpose_to_bf16<<<dim3(48, 16), 256, 0, stream>>>(qkv_w, W1t, 1024, 3072);
  transpose_to_bf16<<<dim3(16, 16), 256, 0, stream>>>(o_w, W2t, 1024, 1024);
  gemm_qkv<<<1536, 256, 0, stream>>>(Xb, W1t, qkv_b, Qb, Kb, Vtb);
  attn<<<1024, 256, 0, stream>>>(Qb, Kb, Vtb, Yb);
  gemm_out_k<<<512, 256, 0, stream>>>(Yb, W2t, o_b, out);
}

// Round 2
// 286.440 us; speedup vs baseline: 1.4184x; 1.4184x over previous
//
#include <hip/hip_runtime.h>

typedef unsigned short ushort_t;
typedef __attribute__((ext_vector_type(8))) short short8;
typedef __attribute__((ext_vector_type(4))) float f32x4;
typedef __attribute__((ext_vector_type(4))) unsigned int uint4v;

__device__ __forceinline__ ushort_t f2bf(float f) {
  union { float f; unsigned int u; } v; v.f = f;
  unsigned int u = v.u;
  unsigned int r = (u + 0x7fffu + ((u >> 16) & 1u)) >> 16;
  return (ushort_t)r;
}

// pack two f32 -> dword of two truncated bf16 (lo from 'lo', hi from 'hi')
__device__ __forceinline__ unsigned int pk2(float hi, float lo) {
  union { float f; unsigned int u; } a, b; a.f = lo; b.f = hi;
  return __builtin_amdgcn_perm(b.u, a.u, 0x07060302u);
}

__device__ __forceinline__ void load_lds16(const void* g, void* l) {
  __builtin_amdgcn_global_load_lds(
      (const __attribute__((address_space(1))) unsigned int*)g,
      (__attribute__((address_space(3))) unsigned int*)l, 16, 0, 0);
}

// ---------------- elementwise f32 -> bf16 ----------------
__global__ __launch_bounds__(256) void cvt_f32_to_bf16_vec(
    const float* __restrict__ in, ushort_t* __restrict__ out, int n8) {
  int i = blockIdx.x * 256 + threadIdx.x;
  if (i >= n8) return;
  const float4* p = (const float4*)in;
  float4 a = p[2 * i];
  float4 b = p[2 * i + 1];
  short8 v;
  v[0] = (short)f2bf(a.x); v[1] = (short)f2bf(a.y);
  v[2] = (short)f2bf(a.z); v[3] = (short)f2bf(a.w);
  v[4] = (short)f2bf(b.x); v[5] = (short)f2bf(b.y);
  v[6] = (short)f2bf(b.z); v[7] = (short)f2bf(b.w);
  *(short8*)(out + (size_t)i * 8) = v;
}

// ---------------- transpose f32 [R][C] -> bf16 [C][R] ----------------
__global__ __launch_bounds__(256) void transpose_to_bf16(
    const float* __restrict__ in, ushort_t* __restrict__ out, int R, int C) {
  __shared__ float tile[64][65];
  int c0 = blockIdx.x * 64, r0 = blockIdx.y * 64;
  int tid = threadIdx.x;
  for (int it = 0; it < 16; ++it) {
    int l = it * 256 + tid;
    int r = l >> 6, c = l & 63;
    tile[r][c] = in[(size_t)(r0 + r) * C + c0 + c];
  }
  __syncthreads();
  for (int it = 0; it < 16; ++it) {
    int l = it * 256 + tid;
    int ro = l >> 6, co = l & 63;
    out[(size_t)(c0 + ro) * R + r0 + co] = f2bf(tile[co][ro]);
  }
}

// ---------------- m97-style gemm_bt core: C[128x128] = A[M][K] * Bt[N][K]^T ----
__device__ __forceinline__ void gemm_bt_main(
    const ushort_t* __restrict__ A, const ushort_t* __restrict__ Bt,
    int K, int bm, int bn, ushort_t* lds, f32x4 acc[4][4]) {
  const int tid = threadIdx.x;
  const int wave = tid >> 6, lane = tid & 63;
  const int quad = lane >> 4, col = lane & 15;
  const int wm = (wave & 1) * 64, wn = (wave >> 1) * 64;
  ushort_t* ldsA = lds;
  ushort_t* ldsB = lds + 8192;
  f32x4 z = {0.f, 0.f, 0.f, 0.f};
  for (int i = 0; i < 4; ++i)
    for (int j = 0; j < 4; ++j) acc[i][j] = z;
  for (int bk = 0; bk < K; bk += 64) {
    for (int is = 0; is < 4; ++is) {
      int o = is * 4096 + wave * 1024 + lane * 16;  // byte offset in 16KB tile
      int p = o >> 13;
      int w = o & 8191;
      int r = w >> 6, kk = (w & 63) >> 1;
      int ldso = (is * 4096 + wave * 1024) >> 1;  // uniform elem offset
      const ushort_t* ga = A + (size_t)(bm + r) * K + bk + p * 32 + kk;
      load_lds16(ga, ldsA + ldso);
      const ushort_t* gb = Bt + (size_t)(bn + r) * K + bk + p * 32 + kk;
      load_lds16(gb, ldsB + ldso);
    }
    __syncthreads();
    for (int ks = 0; ks < 2; ++ks) {
      short8 af[4], bfr[4];
      for (int i = 0; i < 4; ++i)
        af[i] = *(const short8*)(ldsA + ks * 4096 + (wm + i * 16 + col) * 32 + quad * 8);
      for (int j = 0; j < 4; ++j)
        bfr[j] = *(const short8*)(ldsB + ks * 4096 + (wn + j * 16 + col) * 32 + quad * 8);
      for (int i = 0; i < 4; ++i)
        for (int j = 0; j < 4; ++j)
          acc[i][j] = __builtin_amdgcn_mfma_f32_16x16x32_bf16(af[i], bfr[j], acc[i][j], 0, 0, 0);
    }
    __syncthreads();
  }
}

// ---------------- GEMM1: X*W1t^T + b -> Q [bh][t][64], K [bh][t][64], Vt [bh][64][t]
__global__ __launch_bounds__(256) void gemm_qkv(
    const ushort_t* __restrict__ Xb, const ushort_t* __restrict__ W1t,
    const float* __restrict__ bias, ushort_t* __restrict__ Qb,
    ushort_t* __restrict__ Kb, ushort_t* __restrict__ Vtb) {
  __shared__ ushort_t lds[16384];
  const int ntile = 3072 / 128;
  int bn = (blockIdx.x % ntile) * 128;
  int bm = (blockIdx.x / ntile) * 128;
  f32x4 acc[4][4];
  gemm_bt_main(Xb, W1t, 1024, bm, bn, lds, acc);
  const int tid = threadIdx.x, wave = tid >> 6, lane = tid & 63;
  const int quad = lane >> 4, col = lane & 15;
  const int wm = (wave & 1) * 64, wn = (wave >> 1) * 64;
  int which = bn >> 10;  // 0=q, 1=k, 2=v (uniform per block)
  for (int i = 0; i < 4; ++i) {
    int row0 = bm + wm + i * 16 + quad * 4;
    int b = row0 >> 11, t0 = row0 & 2047;
    for (int j = 0; j < 4; ++j) {
      int cg = bn + wn + j * 16 + col;
      float bv = bias[cg];
      int rem = cg & 1023;
      int h = rem >> 6, hd = rem & 63;
      size_t bh = (size_t)(b * 16 + h);
      if (which == 0) {
        for (int r = 0; r < 4; ++r)
          Qb[(bh * 2048 + t0 + r) * 64 + hd] = f2bf(acc[i][j][r] + bv);
      } else if (which == 1) {
        for (int r = 0; r < 4; ++r)
          Kb[(bh * 2048 + t0 + r) * 64 + hd] = f2bf(acc[i][j][r] + bv);
      } else {
        ushort4 pk;
        pk.x = f2bf(acc[i][j][0] + bv);
        pk.y = f2bf(acc[i][j][1] + bv);
        pk.z = f2bf(acc[i][j][2] + bv);
        pk.w = f2bf(acc[i][j][3] + bv);
        *(ushort4*)(Vtb + (bh * 64 + hd) * 2048 + t0) = pk;
      }
    }
  }
}

// ---------------- GEMM2: Y*W2t^T + b -> out (fp32) ----------------
__global__ __launch_bounds__(256) void gemm_out_k(
    const ushort_t* __restrict__ Yb, const ushort_t* __restrict__ W2t,
    const float* __restrict__ bias, float* __restrict__ out) {
  __shared__ ushort_t lds[16384];
  const int ntile = 1024 / 128;
  int bn = (blockIdx.x % ntile) * 128;
  int bm = (blockIdx.x / ntile) * 128;
  f32x4 acc[4][4];
  gemm_bt_main(Yb, W2t, 1024, bm, bn, lds, acc);
  const int tid = threadIdx.x, wave = tid >> 6, lane = tid & 63;
  const int quad = lane >> 4, col = lane & 15;
  const int wm = (wave & 1) * 64, wn = (wave >> 1) * 64;
  for (int i = 0; i < 4; ++i) {
    int row0 = bm + wm + i * 16 + quad * 4;
    for (int j = 0; j < 4; ++j) {
      int cg = bn + wn + j * 16 + col;
      float bv = bias[cg];
      for (int r = 0; r < 4; ++r)
        out[(size_t)(row0 + r) * 1024 + cg] = acc[i][j][r] + bv;
    }
  }
}

// ---------------- flash attention, transposed-S formulation ----------------
// Q,K: [bh][2048][64] bf16; Vt: [bh][64][2048] bf16; Y: [b][t][1024] bf16.
// Block: 128 queries of one (b,h); 4 waves x 32q. k-tiles of 128, causal.
// S^T = K*Q^T via mfma(A=K-rows, B=Q-rows): C-layout D[k=quad*4+r][q=col].
// P^T feeds PV directly as B-operand via permuted-k contraction:
//   B slot (quad g, j) := global k = 32p + 16*(j>=4) + 4g + (j&3)
// V staged into LDS pre-permuted so A-frags are contiguous b128 reads.
#define KS_OFF 0      // K tile [128][72] elems (also Q staging before k-loop)
#define VS_OFF 9216   // V tile [64][136] elems, k-permuted within 32-groups
__global__ __launch_bounds__(256) void attn(
    const ushort_t* __restrict__ Qb, const ushort_t* __restrict__ Kb,
    const ushort_t* __restrict__ Vtb, ushort_t* __restrict__ Yb) {
  __shared__ ushort_t lds[17920];  // 35840 B
  const int tid = threadIdx.x, wave = tid >> 6, lane = tid & 63;
  const int quad = lane >> 4, col = lane & 15;
  int bh = blockIdx.x & 63;
  int qt = 15 - (blockIdx.x >> 6);  // long blocks dispatch first
  int q0 = qt * 128;
  int b = bh >> 4, h = bh & 15;
  const ushort_t* Qg = Qb + (size_t)bh * 2048 * 64;
  const ushort_t* Kg = Kb + (size_t)bh * 2048 * 64;
  const ushort_t* Vg = Vtb + (size_t)bh * 64 * 2048;

  // stage Q tile (stride 72) into KS region, cache B-operand frags in regs
  for (int it = 0; it < 4; ++it) {
    int v = it * 256 + tid;
    int r = v >> 3, co = (v & 7) * 8;
    short8 val = *(const short8*)(Qg + (size_t)(q0 + r) * 64 + co);
    *(short8*)(lds + KS_OFF + r * 72 + co) = val;
  }
  __syncthreads();
  short8 qf[2][2];  // [i][ks]: col q = lane&15 (within 16-tile i), d = ks*32+quad*8+j
  for (int i = 0; i < 2; ++i)
    for (int ks = 0; ks < 2; ++ks)
      qf[i][ks] = *(const short8*)(lds + KS_OFF + (wave * 32 + i * 16 + col) * 72 + ks * 32 + quad * 8);

  f32x4 z = {0.f, 0.f, 0.f, 0.f};
  f32x4 oacc[2][4];  // O^T C-layout: [i qtile][dtile], col=q, row=d
  float mst[2] = {-3.0e38f, -3.0e38f}, lst[2] = {0.f, 0.f};
  for (int i = 0; i < 2; ++i)
    for (int dt = 0; dt < 4; ++dt) oacc[i][dt] = z;
  const float CL = 0.18033688011112042f;  // 0.125 * log2(e)

  for (int kt = 0; kt <= qt; ++kt) {
    int k0 = kt * 128;
    __syncthreads();  // prior LDS consumers done (qf reads at kt=0, frags else)
    for (int it = 0; it < 4; ++it) {  // K tile [128][72]
      int v = it * 256 + tid;
      int r = v >> 3, co = (v & 7) * 8;
      short8 val = *(const short8*)(Kg + (size_t)(k0 + r) * 64 + co);
      *(short8*)(lds + KS_OFF + r * 72 + co) = val;
    }
    for (int it = 0; it < 4; ++it) {  // V tile [64][136], permuted within 32-k groups
      int v = it * 256 + tid;
      int d = v >> 4, m = v & 15;
      int kc = m * 8;
      short8 val = *(const short8*)(Vg + (size_t)d * 2048 + k0 + kc);
      int p = kc >> 5, u = (kc >> 4) & 1, g0 = (kc >> 2) & 3;
      int pos1 = p * 32 + g0 * 8 + u * 4;
      ushort4 lo4, hi4;
      lo4.x = (ushort_t)val[0]; lo4.y = (ushort_t)val[1];
      lo4.z = (ushort_t)val[2]; lo4.w = (ushort_t)val[3];
      hi4.x = (ushort_t)val[4]; hi4.y = (ushort_t)val[5];
      hi4.z = (ushort_t)val[6]; hi4.w = (ushort_t)val[7];
      *(ushort4*)(lds + VS_OFF + d * 136 + pos1) = lo4;
      *(ushort4*)(lds + VS_OFF + d * 136 + pos1 + 8) = hi4;
    }
    __syncthreads();
    // S^T = K Q^T : per wave 128k x 32q
    f32x4 s[2][8];
    for (int i = 0; i < 2; ++i)
      for (int j = 0; j < 8; ++j) s[i][j] = z;
    for (int j = 0; j < 8; ++j) {
      short8 kf0 = *(const short8*)(lds + KS_OFF + (j * 16 + col) * 72 + quad * 8);
      short8 kf1 = *(const short8*)(lds + KS_OFF + (j * 16 + col) * 72 + 32 + quad * 8);
      for (int i = 0; i < 2; ++i) {
        s[i][j] = __builtin_amdgcn_mfma_f32_16x16x32_bf16(kf0, qf[i][0], s[i][j], 0, 0, 0);
        s[i][j] = __builtin_amdgcn_mfma_f32_16x16x32_bf16(kf1, qf[i][1], s[i][j], 0, 0, 0);
      }
    }
    if (kt == qt) {  // diagonal causal mask: k > q -> -inf
      for (int i = 0; i < 2; ++i) {
        int qg = q0 + wave * 32 + i * 16 + col;
        for (int j = 0; j < 8; ++j) {
          int kg = k0 + j * 16 + quad * 4;
          for (int r = 0; r < 4; ++r)
            if (kg + r > qg) s[i][j][r] = -3.0e38f;
        }
      }
    }
    // online softmax: q is fixed per lane (col); k spans regs (j,r) x quads
    for (int i = 0; i < 2; ++i) {
      f32x4 vm = s[i][0];
      for (int j = 1; j < 8; ++j)
        for (int r = 0; r < 4; ++r) vm[r] = fmaxf(vm[r], s[i][j][r]);
      float rm = fmaxf(fmaxf(vm[0], vm[1]), fmaxf(vm[2], vm[3]));
      rm = fmaxf(rm, __shfl_xor(rm, 16));
      rm = fmaxf(rm, __shfl_xor(rm, 32));
      float mnew = fmaxf(mst[i], rm);
      float alpha = __builtin_amdgcn_exp2f((mst[i] - mnew) * CL);
      mst[i] = mnew;
      float mb = mnew * CL;
      float rs = 0.f;
      for (int j = 0; j < 8; ++j)
        for (int r = 0; r < 4; ++r) {
          float p = __builtin_amdgcn_exp2f(fmaf(s[i][j][r], CL, -mb));
          s[i][j][r] = p;
          rs += p;
        }
      rs += __shfl_xor(rs, 16);
      rs += __shfl_xor(rs, 32);
      lst[i] = lst[i] * alpha + rs;
      for (int dt = 0; dt < 4; ++dt)
        for (int r = 0; r < 4; ++r) oacc[i][dt][r] *= alpha;
    }
    // O^T += V^T P^T with permuted-k 32-chunks (pairs of 16-k S^T tiles)
    for (int p2 = 0; p2 < 4; ++p2) {
      short8 pf[2];
      for (int i = 0; i < 2; ++i) {
        uint4v w;
        w[0] = pk2(s[i][2 * p2][1], s[i][2 * p2][0]);
        w[1] = pk2(s[i][2 * p2][3], s[i][2 * p2][2]);
        w[2] = pk2(s[i][2 * p2 + 1][1], s[i][2 * p2 + 1][0]);
        w[3] = pk2(s[i][2 * p2 + 1][3], s[i][2 * p2 + 1][2]);
        pf[i] = *(short8*)&w;
      }
      for (int dt = 0; dt < 4; ++dt) {
        short8 vf = *(const short8*)(lds + VS_OFF + (dt * 16 + col) * 136 + p2 * 32 + quad * 8);
        for (int i = 0; i < 2; ++i)
          oacc[i][dt] = __builtin_amdgcn_mfma_f32_16x16x32_bf16(vf, pf[i], oacc[i][dt], 0, 0, 0);
      }
    }
  }
  // normalize + store Y [b][t][1024]; O^T C-layout: row=d=quad*4+r (contiguous r!)
  for (int i = 0; i < 2; ++i) {
    float linv = 1.0f / lst[i];
    int t = q0 + wave * 32 + i * 16 + col;
    size_t base = ((size_t)(b * 2048 + t)) * 1024 + h * 64;
    for (int dt = 0; dt < 4; ++dt) {
      ushort4 pk;
      pk.x = f2bf(oacc[i][dt][0] * linv);
      pk.y = f2bf(oacc[i][dt][1] * linv);
      pk.z = f2bf(oacc[i][dt][2] * linv);
      pk.w = f2bf(oacc[i][dt][3] * linv);
      *(ushort4*)(Yb + base + dt * 16 + quad * 4) = pk;
    }
  }
}

extern "C" void kernel_launch(void* const* d_in, const int* in_sizes, int n_in,
                              void* d_out, int out_size, void* d_ws, size_t ws_size,
                              hipStream_t stream) {
  const float* x     = (const float*)d_in[0];
  const float* qkv_w = (const float*)d_in[1];
  const float* qkv_b = (const float*)d_in[2];
  const float* o_w   = (const float*)d_in[3];
  const float* o_b   = (const float*)d_in[4];
  float* out = (float*)d_out;
  char* ws = (char*)d_ws;
  ushort_t* Xb  = (ushort_t*)(ws);              // 16 MB (aliased as Yb later)
  ushort_t* W1t = (ushort_t*)(ws + 16777216);   // 6 MB  [3072][1024]
  ushort_t* W2t = (ushort_t*)(ws + 23068672);   // 2 MB  [1024][1024]
  ushort_t* Qb  = (ushort_t*)(ws + 25165824);   // 16 MB [64][2048][64]
  ushort_t* Kb  = (ushort_t*)(ws + 41943040);   // 16 MB
  ushort_t* Vtb = (ushort_t*)(ws + 58720256);   // 16 MB [64][64][2048]
  ushort_t* Yb  = Xb;                           // alias: X dead after gemm_qkv

  cvt_f32_to_bf16_vec<<<4096, 256, 0, stream>>>(x, Xb, 1048576);
  transpose_to_bf16<<<dim3(48, 16), 256, 0, stream>>>(qkv_w, W1t, 1024, 3072);
  transpose_to_bf16<<<dim3(16, 16), 256, 0, stream>>>(o_w, W2t, 1024, 1024);
  gemm_qkv<<<1536, 256, 0, stream>>>(Xb, W1t, qkv_b, Qb, Kb, Vtb);
  attn<<<1024, 256, 0, stream>>>(Qb, Kb, Vtb, Yb);
  gemm_out_k<<<512, 256, 0, stream>>>(Yb, W2t, o_b, out);
}

// Round 3
// 258.418 us; speedup vs baseline: 1.5722x; 1.1084x over previous
//
#include <hip/hip_runtime.h>

typedef unsigned short ushort_t;
typedef __attribute__((ext_vector_type(8))) short short8;
typedef __attribute__((ext_vector_type(4))) float f32x4;
typedef __attribute__((ext_vector_type(4))) unsigned int uint4v;

__device__ __forceinline__ ushort_t f2bf(float f) {
  union { float f; unsigned int u; } v; v.f = f;
  unsigned int u = v.u;
  unsigned int r = (u + 0x7fffu + ((u >> 16) & 1u)) >> 16;
  return (ushort_t)r;
}

// pack two f32 -> dword of two truncated bf16 (lo from 'lo', hi from 'hi')
__device__ __forceinline__ unsigned int pk2(float hi, float lo) {
  union { float f; unsigned int u; } a, b; a.f = lo; b.f = hi;
  return __builtin_amdgcn_perm(b.u, a.u, 0x07060302u);
}

__device__ __forceinline__ void load_lds16(const void* g, void* l) {
  __builtin_amdgcn_global_load_lds(
      (const __attribute__((address_space(1))) unsigned int*)g,
      (__attribute__((address_space(3))) unsigned int*)l, 16, 0, 0);
}

// ---------------- elementwise f32 -> bf16 ----------------
__global__ __launch_bounds__(256) void cvt_f32_to_bf16_vec(
    const float* __restrict__ in, ushort_t* __restrict__ out, int n8) {
  int i = blockIdx.x * 256 + threadIdx.x;
  if (i >= n8) return;
  const float4* p = (const float4*)in;
  float4 a = p[2 * i];
  float4 b = p[2 * i + 1];
  short8 v;
  v[0] = (short)f2bf(a.x); v[1] = (short)f2bf(a.y);
  v[2] = (short)f2bf(a.z); v[3] = (short)f2bf(a.w);
  v[4] = (short)f2bf(b.x); v[5] = (short)f2bf(b.y);
  v[6] = (short)f2bf(b.z); v[7] = (short)f2bf(b.w);
  *(short8*)(out + (size_t)i * 8) = v;
}

// ---------------- transpose f32 [R][C] -> bf16 [C][R] ----------------
__global__ __launch_bounds__(256) void transpose_to_bf16(
    const float* __restrict__ in, ushort_t* __restrict__ out, int R, int C) {
  __shared__ float tile[64][65];
  int c0 = blockIdx.x * 64, r0 = blockIdx.y * 64;
  int tid = threadIdx.x;
  for (int it = 0; it < 16; ++it) {
    int l = it * 256 + tid;
    int r = l >> 6, c = l & 63;
    tile[r][c] = in[(size_t)(r0 + r) * C + c0 + c];
  }
  __syncthreads();
  for (int it = 0; it < 16; ++it) {
    int l = it * 256 + tid;
    int ro = l >> 6, co = l & 63;
    out[(size_t)(c0 + ro) * R + r0 + co] = f2bf(tile[co][ro]);
  }
}

// ---------------- m97-style gemm_bt core: C[128x128] = A[M][K] * Bt[N][K]^T ----
__device__ __forceinline__ void gemm_bt_main(
    const ushort_t* __restrict__ A, const ushort_t* __restrict__ Bt,
    int K, int bm, int bn, ushort_t* lds, f32x4 acc[4][4]) {
  const int tid = threadIdx.x;
  const int wave = tid >> 6, lane = tid & 63;
  const int quad = lane >> 4, col = lane & 15;
  const int wm = (wave & 1) * 64, wn = (wave >> 1) * 64;
  ushort_t* ldsA = lds;
  ushort_t* ldsB = lds + 8192;
  f32x4 z = {0.f, 0.f, 0.f, 0.f};
  for (int i = 0; i < 4; ++i)
    for (int j = 0; j < 4; ++j) acc[i][j] = z;
  for (int bk = 0; bk < K; bk += 64) {
    for (int is = 0; is < 4; ++is) {
      int o = is * 4096 + wave * 1024 + lane * 16;  // byte offset in 16KB tile
      int p = o >> 13;
      int w = o & 8191;
      int r = w >> 6, kk = (w & 63) >> 1;
      int ldso = (is * 4096 + wave * 1024) >> 1;  // uniform elem offset
      const ushort_t* ga = A + (size_t)(bm + r) * K + bk + p * 32 + kk;
      load_lds16(ga, ldsA + ldso);
      const ushort_t* gb = Bt + (size_t)(bn + r) * K + bk + p * 32 + kk;
      load_lds16(gb, ldsB + ldso);
    }
    __syncthreads();
    for (int ks = 0; ks < 2; ++ks) {
      short8 af[4], bfr[4];
      for (int i = 0; i < 4; ++i)
        af[i] = *(const short8*)(ldsA + ks * 4096 + (wm + i * 16 + col) * 32 + quad * 8);
      for (int j = 0; j < 4; ++j)
        bfr[j] = *(const short8*)(ldsB + ks * 4096 + (wn + j * 16 + col) * 32 + quad * 8);
      for (int i = 0; i < 4; ++i)
        for (int j = 0; j < 4; ++j)
          acc[i][j] = __builtin_amdgcn_mfma_f32_16x16x32_bf16(af[i], bfr[j], acc[i][j], 0, 0, 0);
    }
    __syncthreads();
  }
}

// ---------------- GEMM1: X*W1t^T + b -> Q(scaled) [bh][t][64], K [bh][t][64], Vt [bh][64][t]
// Q is pre-scaled by 0.125*log2(e) so attention softmax works in exp2 domain
// with a bare subtract.
__global__ __launch_bounds__(256) void gemm_qkv(
    const ushort_t* __restrict__ Xb, const ushort_t* __restrict__ W1t,
    const float* __restrict__ bias, ushort_t* __restrict__ Qb,
    ushort_t* __restrict__ Kb, ushort_t* __restrict__ Vtb) {
  __shared__ ushort_t lds[16384];
  const int ntile = 3072 / 128;
  int bn = (blockIdx.x % ntile) * 128;
  int bm = (blockIdx.x / ntile) * 128;
  f32x4 acc[4][4];
  gemm_bt_main(Xb, W1t, 1024, bm, bn, lds, acc);
  const int tid = threadIdx.x, wave = tid >> 6, lane = tid & 63;
  const int quad = lane >> 4, col = lane & 15;
  const int wm = (wave & 1) * 64, wn = (wave >> 1) * 64;
  const float SCL = 0.18033688011112042f;  // 0.125 * log2(e)
  int which = bn >> 10;  // 0=q, 1=k, 2=v (uniform per block)
  for (int i = 0; i < 4; ++i) {
    int row0 = bm + wm + i * 16 + quad * 4;
    int b = row0 >> 11, t0 = row0 & 2047;
    for (int j = 0; j < 4; ++j) {
      int cg = bn + wn + j * 16 + col;
      float bv = bias[cg];
      int rem = cg & 1023;
      int h = rem >> 6, hd = rem & 63;
      size_t bh = (size_t)(b * 16 + h);
      if (which == 0) {
        for (int r = 0; r < 4; ++r)
          Qb[(bh * 2048 + t0 + r) * 64 + hd] = f2bf((acc[i][j][r] + bv) * SCL);
      } else if (which == 1) {
        for (int r = 0; r < 4; ++r)
          Kb[(bh * 2048 + t0 + r) * 64 + hd] = f2bf(acc[i][j][r] + bv);
      } else {
        ushort4 pk;
        pk.x = f2bf(acc[i][j][0] + bv);
        pk.y = f2bf(acc[i][j][1] + bv);
        pk.z = f2bf(acc[i][j][2] + bv);
        pk.w = f2bf(acc[i][j][3] + bv);
        *(ushort4*)(Vtb + (bh * 64 + hd) * 2048 + t0) = pk;
      }
    }
  }
}

// ---------------- GEMM2: Y*W2t^T + b -> out (fp32) ----------------
__global__ __launch_bounds__(256) void gemm_out_k(
    const ushort_t* __restrict__ Yb, const ushort_t* __restrict__ W2t,
    const float* __restrict__ bias, float* __restrict__ out) {
  __shared__ ushort_t lds[16384];
  const int ntile = 1024 / 128;
  int bn = (blockIdx.x % ntile) * 128;
  int bm = (blockIdx.x / ntile) * 128;
  f32x4 acc[4][4];
  gemm_bt_main(Yb, W2t, 1024, bm, bn, lds, acc);
  const int tid = threadIdx.x, wave = tid >> 6, lane = tid & 63;
  const int quad = lane >> 4, col = lane & 15;
  const int wm = (wave & 1) * 64, wn = (wave >> 1) * 64;
  for (int i = 0; i < 4; ++i) {
    int row0 = bm + wm + i * 16 + quad * 4;
    for (int j = 0; j < 4; ++j) {
      int cg = bn + wn + j * 16 + col;
      float bv = bias[cg];
      for (int r = 0; r < 4; ++r)
        out[(size_t)(row0 + r) * 1024 + cg] = acc[i][j][r] + bv;
    }
  }
}

// ---------------- flash attention, transposed-S, balanced persistent ----------
// Q(pre-scaled),K: [bh][2048][64] bf16; Vt: [bh][64][2048] bf16; Y: [b][t][1024].
// 512 blocks; block (a=blk>>6, bh=blk&63) processes q-tile 15-a then q-tile a
// => exactly 17 k-tiles per block (perfect balance, 2 blocks/CU all resident).
// K/V tile kt+1 prefetched into registers during compute of kt.
// S^T = K*Q^T; P^T feeds PV as B-operand via permuted-k contraction;
// V staged into LDS pre-permuted (verified in R2).
#define KS_OFF 0      // K tile [128][72] elems
#define VS_OFF 9216   // V tile [64][136] elems, k-permuted within 32-groups
__global__ __launch_bounds__(256, 2) void attn(
    const ushort_t* __restrict__ Qb, const ushort_t* __restrict__ Kb,
    const ushort_t* __restrict__ Vtb, ushort_t* __restrict__ Yb) {
  __shared__ ushort_t lds[17920];  // 35840 B
  const int tid = threadIdx.x, wave = tid >> 6, lane = tid & 63;
  const int quad = lane >> 4, col = lane & 15;
  const int bh = blockIdx.x & 63;
  const int a = blockIdx.x >> 6;  // 0..7
  const int b = bh >> 4, h = bh & 15;
  const ushort_t* Qg = Qb + (size_t)bh * 2048 * 64;
  const ushort_t* Kg = Kb + (size_t)bh * 2048 * 64;
  const ushort_t* Vg = Vtb + (size_t)bh * 64 * 2048;
  // staging index precompute (per thread, loop-invariant)
  const int kv = tid;  // base for it*256+tid
  f32x4 z = {0.f, 0.f, 0.f, 0.f};

  for (int item = 0; item < 2; ++item) {
    const int qt = item == 0 ? 15 - a : a;
    const int q0 = qt * 128;
    // Q frags straight from global (64B-segment coalesced, L2-friendly)
    short8 qf[2][2];
    for (int i = 0; i < 2; ++i)
      for (int ks = 0; ks < 2; ++ks)
        qf[i][ks] = *(const short8*)(
            Qg + (size_t)(q0 + wave * 32 + i * 16 + col) * 64 + ks * 32 + quad * 8);
    // prefetch K/V tile kt=0 into registers
    short8 kpre[4], vpre[4];
#pragma unroll
    for (int it = 0; it < 4; ++it) {
      int v = it * 256 + kv;
      kpre[it] = *(const short8*)(Kg + (size_t)(0 + (v >> 3)) * 64 + (v & 7) * 8);
      vpre[it] = *(const short8*)(Vg + (size_t)(v >> 4) * 2048 + 0 + (v & 15) * 8);
    }

    f32x4 oacc[2][4];
    float mst[2] = {-3.0e38f, -3.0e38f}, lst[2] = {0.f, 0.f};
    for (int i = 0; i < 2; ++i)
      for (int dt = 0; dt < 4; ++dt) oacc[i][dt] = z;

    for (int kt = 0; kt <= qt; ++kt) {
      int k0 = kt * 128;
      __syncthreads();  // all consumers of previous LDS contents done
      // write prefetched K tile [128][72]
#pragma unroll
      for (int it = 0; it < 4; ++it) {
        int v = it * 256 + kv;
        *(short8*)(lds + KS_OFF + (v >> 3) * 72 + (v & 7) * 8) = kpre[it];
      }
      // write prefetched V tile [64][136], permuted within 32-k groups
#pragma unroll
      for (int it = 0; it < 4; ++it) {
        int v = it * 256 + kv;
        int d = v >> 4, kc = (v & 15) * 8;
        int p = kc >> 5, u = (kc >> 4) & 1, g0 = (kc >> 2) & 3;
        int pos1 = p * 32 + g0 * 8 + u * 4;
        short8 val = vpre[it];
        ushort4 lo4, hi4;
        lo4.x = (ushort_t)val[0]; lo4.y = (ushort_t)val[1];
        lo4.z = (ushort_t)val[2]; lo4.w = (ushort_t)val[3];
        hi4.x = (ushort_t)val[4]; hi4.y = (ushort_t)val[5];
        hi4.z = (ushort_t)val[6]; hi4.w = (ushort_t)val[7];
        *(ushort4*)(lds + VS_OFF + d * 136 + pos1) = lo4;
        *(ushort4*)(lds + VS_OFF + d * 136 + pos1 + 8) = hi4;
      }
      __syncthreads();
      // issue prefetch for kt+1 (overlaps with compute below)
      if (kt < qt) {
        int k0n = k0 + 128;
#pragma unroll
        for (int it = 0; it < 4; ++it) {
          int v = it * 256 + kv;
          kpre[it] = *(const short8*)(Kg + (size_t)(k0n + (v >> 3)) * 64 + (v & 7) * 8);
          vpre[it] = *(const short8*)(Vg + (size_t)(v >> 4) * 2048 + k0n + (v & 15) * 8);
        }
      }
      // S^T = K Q^T : per wave 128k x 32q
      f32x4 s[2][8];
      for (int i = 0; i < 2; ++i)
        for (int j = 0; j < 8; ++j) s[i][j] = z;
      for (int j = 0; j < 8; ++j) {
        short8 kf0 = *(const short8*)(lds + KS_OFF + (j * 16 + col) * 72 + quad * 8);
        short8 kf1 = *(const short8*)(lds + KS_OFF + (j * 16 + col) * 72 + 32 + quad * 8);
        for (int i = 0; i < 2; ++i) {
          s[i][j] = __builtin_amdgcn_mfma_f32_16x16x32_bf16(kf0, qf[i][0], s[i][j], 0, 0, 0);
          s[i][j] = __builtin_amdgcn_mfma_f32_16x16x32_bf16(kf1, qf[i][1], s[i][j], 0, 0, 0);
        }
      }
      if (kt == qt) {  // diagonal causal mask: k > q -> -inf
        for (int i = 0; i < 2; ++i) {
          int qg = q0 + wave * 32 + i * 16 + col;
          for (int j = 0; j < 8; ++j) {
            int kg = k0 + j * 16 + quad * 4;
            for (int r = 0; r < 4; ++r)
              if (kg + r > qg) s[i][j][r] = -3.0e38f;
          }
        }
      }
      // online softmax in exp2 domain (Q pre-scaled by 0.125*log2e)
      for (int i = 0; i < 2; ++i) {
        f32x4 vm = s[i][0];
        for (int j = 1; j < 8; ++j)
          for (int r = 0; r < 4; ++r) vm[r] = fmaxf(vm[r], s[i][j][r]);
        float rm = fmaxf(fmaxf(vm[0], vm[1]), fmaxf(vm[2], vm[3]));
        rm = fmaxf(rm, __shfl_xor(rm, 16));
        rm = fmaxf(rm, __shfl_xor(rm, 32));
        float mnew = fmaxf(mst[i], rm);
        float alpha = __builtin_amdgcn_exp2f(mst[i] - mnew);
        mst[i] = mnew;
        float rs = 0.f;
        for (int j = 0; j < 8; ++j)
          for (int r = 0; r < 4; ++r) {
            float p = __builtin_amdgcn_exp2f(s[i][j][r] - mnew);
            s[i][j][r] = p;
            rs += p;
          }
        rs += __shfl_xor(rs, 16);
        rs += __shfl_xor(rs, 32);
        lst[i] = lst[i] * alpha + rs;
        for (int dt = 0; dt < 4; ++dt)
          for (int r = 0; r < 4; ++r) oacc[i][dt][r] *= alpha;
      }
      // O^T += V^T P^T with permuted-k 32-chunks (pairs of 16-k S^T tiles)
      for (int p2 = 0; p2 < 4; ++p2) {
        short8 pf[2];
        for (int i = 0; i < 2; ++i) {
          uint4v w;
          w[0] = pk2(s[i][2 * p2][1], s[i][2 * p2][0]);
          w[1] = pk2(s[i][2 * p2][3], s[i][2 * p2][2]);
          w[2] = pk2(s[i][2 * p2 + 1][1], s[i][2 * p2 + 1][0]);
          w[3] = pk2(s[i][2 * p2 + 1][3], s[i][2 * p2 + 1][2]);
          pf[i] = *(short8*)&w;
        }
        for (int dt = 0; dt < 4; ++dt) {
          short8 vf = *(const short8*)(lds + VS_OFF + (dt * 16 + col) * 136 + p2 * 32 + quad * 8);
          for (int i = 0; i < 2; ++i)
            oacc[i][dt] = __builtin_amdgcn_mfma_f32_16x16x32_bf16(vf, pf[i], oacc[i][dt], 0, 0, 0);
        }
      }
    }
    // normalize + store Y [b][t][1024]; O^T C-layout row=d (contiguous r)
    for (int i = 0; i < 2; ++i) {
      float linv = 1.0f / lst[i];
      int t = q0 + wave * 32 + i * 16 + col;
      size_t base = ((size_t)(b * 2048 + t)) * 1024 + h * 64;
      for (int dt = 0; dt < 4; ++dt) {
        ushort4 pk;
        pk.x = f2bf(oacc[i][dt][0] * linv);
        pk.y = f2bf(oacc[i][dt][1] * linv);
        pk.z = f2bf(oacc[i][dt][2] * linv);
        pk.w = f2bf(oacc[i][dt][3] * linv);
        *(ushort4*)(Yb + base + dt * 16 + quad * 4) = pk;
      }
    }
  }
}

extern "C" void kernel_launch(void* const* d_in, const int* in_sizes, int n_in,
                              void* d_out, int out_size, void* d_ws, size_t ws_size,
                              hipStream_t stream) {
  const float* x     = (const float*)d_in[0];
  const float* qkv_w = (const float*)d_in[1];
  const float* qkv_b = (const float*)d_in[2];
  const float* o_w   = (const float*)d_in[3];
  const float* o_b   = (const float*)d_in[4];
  float* out = (float*)d_out;
  char* ws = (char*)d_ws;
  ushort_t* Xb  = (ushort_t*)(ws);              // 16 MB (aliased as Yb later)
  ushort_t* W1t = (ushort_t*)(ws + 16777216);   // 6 MB  [3072][1024]
  ushort_t* W2t = (ushort_t*)(ws + 23068672);   // 2 MB  [1024][1024]
  ushort_t* Qb  = (ushort_t*)(ws + 25165824);   // 16 MB [64][2048][64] (pre-scaled)
  ushort_t* Kb  = (ushort_t*)(ws + 41943040);   // 16 MB
  ushort_t* Vtb = (ushort_t*)(ws + 58720256);   // 16 MB [64][64][2048]
  ushort_t* Yb  = Xb;                           // alias: X dead after gemm_qkv

  cvt_f32_to_bf16_vec<<<4096, 256, 0, stream>>>(x, Xb, 1048576);
  transpose_to_bf16<<<dim3(48, 16), 256, 0, stream>>>(qkv_w, W1t, 1024, 3072);
  transpose_to_bf16<<<dim3(16, 16), 256, 0, stream>>>(o_w, W2t, 1024, 1024);
  gemm_qkv<<<1536, 256, 0, stream>>>(Xb, W1t, qkv_b, Qb, Kb, Vtb);
  attn<<<512, 256, 0, stream>>>(Qb, Kb, Vtb, Yb);
  gemm_out_k<<<512, 256, 0, stream>>>(Yb, W2t, o_b, out);
}